// Round 7
// baseline (172.257 us; speedup 1.0000x reference)
//
#include <hip/hip_runtime.h>
#include <math.h>

#define NUM_CLASSES 124
#define FEAT_CH     64
#define OUT_HW      480
#define IN_HW       120
#define NPIX        (OUT_HW * OUT_HW)
#define NCELL       (IN_HW * IN_HW)
#define NQUAD       (NPIX / 4)          // 57600 quads
#define EPSV        1e-8f

#define STRIDE_ACC   65
#define ACC_FLOATS   (NUM_CLASSES * STRIDE_ACC)        // 8060
#define ACC_TOTAL    (ACC_FLOATS + NUM_CLASSES)        // 8184

// ws layout (floats): mn[7936] | acc[8184] | fT[14400*64] | part[nb*8184]
#define WS_MN   0
#define WS_ACC  (NUM_CLASSES * FEAT_CH)
#define WS_FT   (WS_ACC + ACC_TOTAL)
#define WS_PART (WS_FT + NCELL * FEAT_CH)

#define NTILE   (NCELL / 64)            // 225 transpose tiles
#define NRED    8                       // reduce: partial chunks per slot

// ---- phase 0 (fused): normalize memory, zero acc, LDS-tiled transpose --------
__global__ __launch_bounds__(256) void k_prep(
        const float* __restrict__ mem, const float* __restrict__ feats,
        float* __restrict__ mn, float* __restrict__ acc, float* __restrict__ fT) {
    const int b = blockIdx.x;
    if (b < NUM_CLASSES) {
        if (threadIdx.x < FEAT_CH) {
            const int c = b, k = threadIdx.x;
            float v = mem[c * FEAT_CH + k];
            float s = v * v;
#pragma unroll
            for (int off = 32; off; off >>= 1) s += __shfl_xor(s, off);
            mn[c * FEAT_CH + k] = v / fmaxf(sqrtf(s), EPSV);
        }
    } else if (b < NUM_CLASSES + 32) {
        const int i = (b - NUM_CLASSES) * 256 + threadIdx.x;
        if (i < ACC_TOTAL) acc[i] = 0.0f;
    } else {
        __shared__ float tileL[64 * 65];
        const int t = b - NUM_CLASSES - 32;        // 0..224
        const int q0 = t * 64;
        const int tid = threadIdx.x;
#pragma unroll
        for (int i = 0; i < 16; ++i) {
            const int idx = i * 256 + tid;
            const int k = idx >> 6, q = idx & 63;  // q fast -> coalesced read
            tileL[q * 65 + k] = feats[k * NCELL + q0 + q];
        }
        __syncthreads();
#pragma unroll
        for (int i = 0; i < 16; ++i) {
            const int idx = i * 256 + tid;
            const int q = idx >> 6, k = idx & 63;  // k fast -> coalesced write
            fT[(q0 + q) * FEAT_CH + k] = tileL[q * 65 + k];
        }
    }
}

// ---- DPP rotational butterfly: all-lanes sum within rows of 16 ---------------
template <int CTRL>
__device__ __forceinline__ float dpp_ror_add(float x) {
    int v = __builtin_amdgcn_update_dpp(0, __float_as_int(x), CTRL, 0xF, 0xF, false);
    return x + __int_as_float(v);
}
__device__ __forceinline__ void reduce16_pair(float& a, float& b) {
    a = dpp_ror_add<0x128>(a); b = dpp_ror_add<0x128>(b);   // row_ror:8
    a = dpp_ror_add<0x124>(a); b = dpp_ror_add<0x124>(b);   // row_ror:4
    a = dpp_ror_add<0x122>(a); b = dpp_ror_add<0x122>(b);   // row_ror:2
    a = dpp_ror_add<0x121>(a); b = dpp_ror_add<0x121>(b);   // row_ror:1
}

// ---- prefetch: issue all global loads for quad Q -----------------------------
__device__ __forceinline__ void issue_loads(int Q, int j, int g,
        const float4* __restrict__ fT4, const int* __restrict__ seg,
        const float4* __restrict__ mn4,
        float4& am, float4& a0, float4& ap,
        float4& bm, float4& b0, float4& bp, int& c, float4& m4) {
    const int oy = Q / 120;
    const int a  = Q - oy * 120;
    float fy = fminf(fmaxf(oy * 0.25f - 0.375f, 0.0f), (float)(IN_HW - 1));
    const int y0 = (int)fy;
    const int y1 = min(y0 + 1, IN_HW - 1);
    const int xm1 = max(a - 1, 0), xp1 = min(a + 1, IN_HW - 1);
    const int r0 = y0 * IN_HW, r1 = y1 * IN_HW;
    am = fT4[(r0 + xm1) * 16 + g];
    a0 = fT4[(r0 + a  ) * 16 + g];
    ap = fT4[(r0 + xp1) * 16 + g];
    bm = fT4[(r1 + xm1) * 16 + g];
    b0 = fT4[(r1 + a  ) * 16 + g];
    bp = fT4[(r1 + xp1) * 16 + g];
    c  = seg[oy * OUT_HW + 4 * a + j];
    m4 = mn4[c * 16 + g];
}

// ---- phase 1: wave = quad (4 px x 16 lanes); plain-store flush ---------------
__global__ __launch_bounds__(1024, 4) void k_accum(
        const float* __restrict__ fT, const int* __restrict__ seg,
        const float* __restrict__ mn, float* __restrict__ part) {
    __shared__ float accL[ACC_FLOATS];
    __shared__ float cntL[NUM_CLASSES];

    const int tid = threadIdx.x;
    for (int i = tid; i < ACC_FLOATS; i += 1024) accL[i] = 0.0f;
    for (int i = tid; i < NUM_CLASSES; i += 1024) cntL[i] = 0.0f;
    __syncthreads();

    const int lane = tid & 63;
    const int j = lane >> 4;          // pixel within quad
    const int g = lane & 15;          // channel group (4 ch)
    const int wid = (blockIdx.x * 1024 + tid) >> 6;
    const int nwaves = gridDim.x * 16;
    const float4* __restrict__ fT4 = (const float4*)fT;
    const float4* __restrict__ mn4 = (const float4*)mn;

    float4 p_am, p_a0, p_ap, p_bm, p_b0, p_bp, p_m4; int p_c;
    issue_loads(min(wid, NQUAD - 1), j, g, fT4, seg, mn4,
                p_am, p_a0, p_ap, p_bm, p_b0, p_bp, p_c, p_m4);

    for (int Q = wid; Q < NQUAD; Q += nwaves) {
        const float4 am = p_am, a0 = p_a0, ap = p_ap;
        const float4 bm = p_bm, b0 = p_b0, bp = p_bp;
        const float4 m4 = p_m4; const int c = p_c;
        const int Qn = Q + nwaves;
        if (Qn < NQUAD)
            issue_loads(Qn, j, g, fT4, seg, mn4,
                        p_am, p_a0, p_ap, p_bm, p_b0, p_bp, p_c, p_m4);

        const int oy = Q / 120;
        const int a  = Q - oy * 120;
        float fy = fminf(fmaxf(oy * 0.25f - 0.375f, 0.0f), (float)(IN_HW - 1));
        const int y0 = (int)fy; const float ty = fy - (float)y0;
        const int ox = 4 * a + j;
        float fx = fminf(fmaxf(ox * 0.25f - 0.375f, 0.0f), (float)(IN_HW - 1));
        const int x0 = (int)fx; const float tx = fx - (float)x0;
        const bool lo = x0 < a;
        const float4 cL = lo ? am : a0;
        const float4 cR = lo ? a0 : ap;
        const float4 dL = lo ? bm : b0;
        const float4 dR = lo ? b0 : bp;

        float4 v;
        {
            float t0, t1;
            t0 = fmaf(tx, cR.x - cL.x, cL.x); t1 = fmaf(tx, dR.x - dL.x, dL.x);
            v.x = fmaf(ty, t1 - t0, t0);
            t0 = fmaf(tx, cR.y - cL.y, cL.y); t1 = fmaf(tx, dR.y - dL.y, dL.y);
            v.y = fmaf(ty, t1 - t0, t0);
            t0 = fmaf(tx, cR.z - cL.z, cL.z); t1 = fmaf(tx, dR.z - dL.z, dL.z);
            v.z = fmaf(ty, t1 - t0, t0);
            t0 = fmaf(tx, cR.w - cL.w, cL.w); t1 = fmaf(tx, dR.w - dL.w, dL.w);
            v.w = fmaf(ty, t1 - t0, t0);
        }
        float nr = fmaf(v.x, v.x, fmaf(v.y, v.y, fmaf(v.z, v.z, v.w * v.w)));
        float dt = fmaf(v.x, m4.x, fmaf(v.y, m4.y, fmaf(v.z, m4.z, v.w * m4.w)));
        reduce16_pair(nr, dt);
        const float w = 1.0f - dt / fmaxf(sqrtf(nr), EPSV); // mn==0 rows -> w==1

        float* __restrict__ arow = accL + c * STRIDE_ACC + 4 * g;
        atomicAdd(&arow[0], w * v.x);
        atomicAdd(&arow[1], w * v.y);
        atomicAdd(&arow[2], w * v.z);
        atomicAdd(&arow[3], w * v.w);
        if (g == 0) {
            atomicAdd(&accL[c * STRIDE_ACC + FEAT_CH], w);
            atomicAdd(&cntL[c], 1.0f);
        }
    }
    __syncthreads();

    // plain coalesced store of this block's partial accumulator
    float* __restrict__ dst = part + (size_t)blockIdx.x * ACC_TOTAL;
    for (int i = tid; i < ACC_FLOATS; i += 1024) dst[i] = accL[i];
    for (int i = tid; i < NUM_CLASSES; i += 1024) dst[ACC_FLOATS + i] = cntL[i];
}

// ---- phase 1b: tree-reduce partials (thread-per-slot x NRED chunks) ----------
__global__ __launch_bounds__(256) void k_reduce(
        const float* __restrict__ part, float* __restrict__ acc, int nb) {
    const int i = blockIdx.x * 256 + threadIdx.x;    // slot
    if (i >= ACC_TOTAL) return;
    const int chunk = (nb + NRED - 1) / NRED;
    const int b0 = blockIdx.y * chunk;
    const int b1 = min(nb, b0 + chunk);
    float s = 0.0f;
    for (int b = b0; b < b1; ++b) s += part[(size_t)b * ACC_TOTAL + i];
    if (s != 0.0f) atomicAdd(&acc[i], s);
}

// ---- phase 2: momentum / is_zero / present selects ---------------------------
__global__ void k_final(const float* __restrict__ acc, const float* __restrict__ mem,
                        float* __restrict__ out) {
    const int c = blockIdx.x, k = threadIdx.x;   // 124 blocks x 64 threads (1 wave)
    const float a    = acc[c * STRIDE_ACC + k];
    const float wsum = acc[c * STRIDE_ACC + FEAT_CH];
    const float cnt  = acc[ACC_FLOATS + c];
    const float m = mem[c * FEAT_CH + k];
    const int is_zero = __all(m == 0.0f);
    const float divisor = (wsum > 0.0f) ? wsum : 1.0f;
    const float val = a / divisor;
    const float nw = is_zero ? val : fmaf(0.1f, val, 0.9f * m);
    out[c * FEAT_CH + k] = (cnt > 0.0f) ? nw : m;
}

extern "C" void kernel_launch(void* const* d_in, const int* in_sizes, int n_in,
                              void* d_out, int out_size, void* d_ws, size_t ws_size,
                              hipStream_t stream) {
    const float* feats  = (const float*)d_in[0];   // (1,64,120,120) f32
    const float* memory = (const float*)d_in[1];   // (124,1,64) f32
    const int*   seg    = (const int*)d_in[2];     // (1,480,480) i32
    float* out = (float*)d_out;                    // (124,1,64) f32
    float* ws  = (float*)d_ws;

    float* mn   = ws + WS_MN;
    float* acc  = ws + WS_ACC;
    float* fT   = ws + WS_FT;
    float* part = ws + WS_PART;

    // loop grid: 512 blocks (2/CU, 32 waves/CU) if workspace allows, else 256
    long long avail = (long long)(ws_size / 4) - WS_PART;
    const int nb = (avail >= (long long)512 * ACC_TOTAL) ? 512 : 256;

    k_prep<<<NUM_CLASSES + 32 + NTILE, 256, 0, stream>>>(memory, feats, mn, acc, fT);
    k_accum<<<nb, 1024, 0, stream>>>(fT, seg, mn, part);
    dim3 rg((ACC_TOTAL + 255) / 256, NRED);
    k_reduce<<<rg, 256, 0, stream>>>(part, acc, nb);
    k_final<<<NUM_CLASSES, FEAT_CH, 0, stream>>>(acc, memory, out);
}

// Round 8
// 129.078 us; speedup vs baseline: 1.3345x; 1.3345x over previous
//
#include <hip/hip_runtime.h>
#include <hip/hip_bf16.h>
#include <math.h>

#define NUM_CLASSES 124
#define NCLS_PAD    128
#define FEAT_CH     64
#define OUT_HW      480
#define IN_HW       120
#define NPIX        (OUT_HW * OUT_HW)
#define NCELL       (IN_HW * IN_HW)
#define NCHUNK      (NPIX / 32)         // 7200 chunks of 32 px (15 per row)
#define EPSV        1e-8f

#define STRIDE_ACC   65
#define ACC_FLOATS   (NCLS_PAD * STRIDE_ACC)           // 8320
#define ACC_TOTAL    (ACC_FLOATS + NCLS_PAD)           // 8448

// ws layout (floats): mn[7936] | acc[8448] | fT[14400*64] | part[nb*8448]
#define WS_MN   0
#define WS_ACC  (NUM_CLASSES * FEAT_CH)
#define WS_FT   (WS_ACC + ACC_TOTAL)
#define WS_PART (WS_FT + NCELL * FEAT_CH)

#define NTILE   (NCELL / 64)            // 225 transpose tiles
#define NZB     ((ACC_TOTAL + 255) / 256)  // 33 zero blocks
#define NRED    8

typedef short  v8s __attribute__((ext_vector_type(8)));
typedef float  v4f __attribute__((ext_vector_type(4)));

__device__ __forceinline__ short f2bf(float x) {
    __hip_bfloat16 h = __float2bfloat16(x);
    return __builtin_bit_cast(short, h);
}

// ---- phase 0 (fused): normalize memory, zero acc, LDS-tiled transpose --------
__global__ __launch_bounds__(256) void k_prep(
        const float* __restrict__ mem, const float* __restrict__ feats,
        float* __restrict__ mn, float* __restrict__ acc, float* __restrict__ fT) {
    const int b = blockIdx.x;
    if (b < NUM_CLASSES) {
        if (threadIdx.x < FEAT_CH) {
            const int c = b, k = threadIdx.x;
            float v = mem[c * FEAT_CH + k];
            float s = v * v;
#pragma unroll
            for (int off = 32; off; off >>= 1) s += __shfl_xor(s, off);
            mn[c * FEAT_CH + k] = v / fmaxf(sqrtf(s), EPSV);
        }
    } else if (b < NUM_CLASSES + NZB) {
        const int i = (b - NUM_CLASSES) * 256 + threadIdx.x;
        if (i < ACC_TOTAL) acc[i] = 0.0f;
    } else {
        __shared__ float tileL[64 * 65];
        const int t = b - NUM_CLASSES - NZB;       // 0..224
        const int q0 = t * 64;
        const int tid = threadIdx.x;
#pragma unroll
        for (int i = 0; i < 16; ++i) {
            const int idx = i * 256 + tid;
            const int k = idx >> 6, q = idx & 63;  // q fast -> coalesced read
            tileL[q * 65 + k] = feats[k * NCELL + q0 + q];
        }
        __syncthreads();
#pragma unroll
        for (int i = 0; i < 16; ++i) {
            const int idx = i * 256 + tid;
            const int q = idx >> 6, k = idx & 63;  // k fast -> coalesced write
            fT[(q0 + q) * FEAT_CH + k] = tileL[q * 65 + k];
        }
    }
}

// ---- DPP rotational butterfly: all-lanes sum within rows of 16 ---------------
template <int CTRL>
__device__ __forceinline__ float dpp_ror_add(float x) {
    int v = __builtin_amdgcn_update_dpp(0, __float_as_int(x), CTRL, 0xF, 0xF, false);
    return x + __int_as_float(v);
}
__device__ __forceinline__ void reduce16_pair(float& a, float& b) {
    a = dpp_ror_add<0x128>(a); b = dpp_ror_add<0x128>(b);   // row_ror:8
    a = dpp_ror_add<0x124>(a); b = dpp_ror_add<0x124>(b);   // row_ror:4
    a = dpp_ror_add<0x122>(a); b = dpp_ror_add<0x122>(b);   // row_ror:2
    a = dpp_ror_add<0x121>(a); b = dpp_ror_add<0x121>(b);   // row_ror:1
}

// ---- phase 1: one-hot MFMA accumulation --------------------------------------
// wave = 32 consecutive pixels (1 chunk). lane = (n=ch-in-tile, kg=pixel-group).
// Each lane computes 8 px x 4 ch-tiles of bilinear x directly in B-fragment
// layout; A = one-hot(seg)*w built in-register; 8 class-bands x 4 ch-tiles of
// 16x16x32 bf16 MFMA accumulate C[128][64] in 128 VGPRs per lane.
__global__ __launch_bounds__(512, 2) void k_accum(
        const float* __restrict__ fT, const int* __restrict__ seg,
        const float* __restrict__ mn, float* __restrict__ part) {
    __shared__ float accL[ACC_FLOATS];
    __shared__ float cntL[NCLS_PAD];

    const int tid = threadIdx.x;
    for (int i = tid; i < ACC_FLOATS; i += 512) accL[i] = 0.0f;
    if (tid < NCLS_PAD) cntL[tid] = 0.0f;
    __syncthreads();

    const int lane = tid & 63;
    const int n  = lane & 15;         // ch within tile / class within band
    const int kg = lane >> 4;         // pixel-group (8 px each)
    const int widx = tid >> 6;        // wave in block (0..7)
    const int gwave = blockIdx.x * 8 + widx;
    const int nw = gridDim.x * 8;

    v4f acc[8][4];
#pragma unroll
    for (int b = 0; b < 8; ++b)
#pragma unroll
        for (int t = 0; t < 4; ++t) acc[b][t] = (v4f)0.0f;

    for (int ch = gwave; ch < NCHUNK; ch += nw) {
        const int oy  = ch / 15;
        const int px0 = (ch - oy * 15) * 32 + kg * 8;   // my first ox
        float fy = fminf(fmaxf(oy * 0.25f - 0.375f, 0.0f), 119.0f);
        const int y0 = (int)fy; const float ty = fy - (float)y0;
        const int y1 = min(y0 + 1, IN_HW - 1);
        const int base = px0 >> 2;                       // integer (px0 % 8 == 0)
        const int c0 = max(base - 1, 0), c1 = base;
        const int c2 = min(base + 1, IN_HW - 1), c3 = min(base + 2, IN_HW - 1);
        const int r0 = y0 * IN_HW, r1 = y1 * IN_HW;

        int segj[8];
        {
            const int4* sp = (const int4*)(seg + oy * OUT_HW + px0);
            int4 s0 = sp[0], s1 = sp[1];
            segj[0]=s0.x; segj[1]=s0.y; segj[2]=s0.z; segj[3]=s0.w;
            segj[4]=s1.x; segj[5]=s1.y; segj[6]=s1.z; segj[7]=s1.w;
        }
        float txj[8]; int Lj[8];
#pragma unroll
        for (int j = 0; j < 8; ++j) {
            float fx = fminf(fmaxf((float)(px0 + j) * 0.25f - 0.375f, 0.0f), 119.0f);
            int x0 = (int)fx; txj[j] = fx - (float)x0; Lj[j] = x0 - base + 1;  // 0..2
        }

        float nr[8], dt[8];
#pragma unroll
        for (int j = 0; j < 8; ++j) { nr[j] = 0.0f; dt[j] = 0.0f; }
        v8s Bfrag[4];
#pragma unroll
        for (int t = 0; t < 4; ++t) {
            const int chn = n + 16 * t;
            const float T0 = fT[(r0+c0)*64+chn], T1 = fT[(r0+c1)*64+chn];
            const float T2 = fT[(r0+c2)*64+chn], T3 = fT[(r0+c3)*64+chn];
            const float B0 = fT[(r1+c0)*64+chn], B1 = fT[(r1+c1)*64+chn];
            const float B2 = fT[(r1+c2)*64+chn], B3 = fT[(r1+c3)*64+chn];
#pragma unroll
            for (int j = 0; j < 8; ++j) {
                const int L = Lj[j];
                float tl = (L==0)?T0:((L==1)?T1:T2);
                float tr = (L==0)?T1:((L==1)?T2:T3);
                float bl = (L==0)?B0:((L==1)?B1:B2);
                float br = (L==0)?B1:((L==1)?B2:B3);
                float top = fmaf(txj[j], tr - tl, tl);
                float bot = fmaf(txj[j], br - bl, bl);
                float v   = fmaf(ty, bot - top, top);
                nr[j] = fmaf(v, v, nr[j]);
                dt[j] = fmaf(v, mn[segj[j] * 64 + chn], dt[j]);
                Bfrag[t][j] = f2bf(v);
            }
        }
        // per-pixel reduce over 16 ch-lanes (within the kg row of 16)
#pragma unroll
        for (int j = 0; j < 8; ++j) reduce16_pair(nr[j], dt[j]);

        float wj[8]; short wb[8];
#pragma unroll
        for (int j = 0; j < 8; ++j) {
            wj[j] = 1.0f - dt[j] / fmaxf(sqrtf(nr[j]), EPSV);  // mn==0 rows -> w==1
            wb[j] = f2bf(wj[j]);
        }
        // one-hot A per class band, 4 MFMAs each
#pragma unroll
        for (int b = 0; b < 8; ++b) {
            v8s A;
#pragma unroll
            for (int j = 0; j < 8; ++j)
                A[j] = (segj[j] == b * 16 + n) ? wb[j] : (short)0;
#pragma unroll
            for (int t = 0; t < 4; ++t)
                acc[b][t] = __builtin_amdgcn_mfma_f32_16x16x32_bf16(A, Bfrag[t], acc[b][t], 0, 0, 0);
        }
        // wsum / count (2 LDS atomics per pixel, lanes n==0 only)
        if (n == 0) {
#pragma unroll
            for (int j = 0; j < 8; ++j) {
                atomicAdd(&accL[segj[j] * STRIDE_ACC + FEAT_CH], wj[j]);
                atomicAdd(&cntL[segj[j]], 1.0f);
            }
        }
    }

    // merge per-wave C into accL (waves sequential; once per block)
    for (int wv = 0; wv < 8; ++wv) {
        __syncthreads();
        if (widx == wv) {
#pragma unroll
            for (int b = 0; b < 8; ++b)
#pragma unroll
                for (int t = 0; t < 4; ++t)
#pragma unroll
                    for (int r = 0; r < 4; ++r) {
                        const int cls = b * 16 + kg * 4 + r;   // C row
                        const int chn = t * 16 + n;            // C col
                        accL[cls * STRIDE_ACC + chn] += acc[b][t][r];
                    }
        }
    }
    __syncthreads();

    float* __restrict__ dst = part + (size_t)blockIdx.x * ACC_TOTAL;
    for (int i = tid; i < ACC_FLOATS; i += 512) dst[i] = accL[i];
    if (tid < NCLS_PAD) dst[ACC_FLOATS + tid] = cntL[tid];
}

// ---- phase 1b: tree-reduce partials ------------------------------------------
__global__ __launch_bounds__(256) void k_reduce(
        const float* __restrict__ part, float* __restrict__ acc, int nb) {
    const int i = blockIdx.x * 256 + threadIdx.x;    // slot
    if (i >= ACC_TOTAL) return;
    const int chunk = (nb + NRED - 1) / NRED;
    const int b0 = blockIdx.y * chunk;
    const int b1 = min(nb, b0 + chunk);
    float s = 0.0f;
    for (int b = b0; b < b1; ++b) s += part[(size_t)b * ACC_TOTAL + i];
    if (s != 0.0f) atomicAdd(&acc[i], s);
}

// ---- phase 2: momentum / is_zero / present selects ---------------------------
__global__ void k_final(const float* __restrict__ acc, const float* __restrict__ mem,
                        float* __restrict__ out) {
    const int c = blockIdx.x, k = threadIdx.x;   // 124 blocks x 64 threads (1 wave)
    const float a    = acc[c * STRIDE_ACC + k];
    const float wsum = acc[c * STRIDE_ACC + FEAT_CH];
    const float cnt  = acc[ACC_FLOATS + c];
    const float m = mem[c * FEAT_CH + k];
    const int is_zero = __all(m == 0.0f);
    const float divisor = (wsum > 0.0f) ? wsum : 1.0f;
    const float val = a / divisor;
    const float nw = is_zero ? val : fmaf(0.1f, val, 0.9f * m);
    out[c * FEAT_CH + k] = (cnt > 0.0f) ? nw : m;
}

extern "C" void kernel_launch(void* const* d_in, const int* in_sizes, int n_in,
                              void* d_out, int out_size, void* d_ws, size_t ws_size,
                              hipStream_t stream) {
    const float* feats  = (const float*)d_in[0];   // (1,64,120,120) f32
    const float* memory = (const float*)d_in[1];   // (124,1,64) f32
    const int*   seg    = (const int*)d_in[2];     // (1,480,480) i32
    float* out = (float*)d_out;                    // (124,1,64) f32
    float* ws  = (float*)d_ws;

    float* mn   = ws + WS_MN;
    float* acc  = ws + WS_ACC;
    float* fT   = ws + WS_FT;
    float* part = ws + WS_PART;

    long long avail = (long long)(ws_size / 4) - WS_PART;
    const int nb = (avail >= (long long)512 * ACC_TOTAL) ? 512 : 256;

    k_prep<<<NUM_CLASSES + NZB + NTILE, 256, 0, stream>>>(memory, feats, mn, acc, fT);
    k_accum<<<nb, 512, 0, stream>>>(fT, seg, mn, part);
    dim3 rg((ACC_TOTAL + 255) / 256, NRED);
    k_reduce<<<rg, 256, 0, stream>>>(part, acc, nb);
    k_final<<<NUM_CLASSES, FEAT_CH, 0, stream>>>(acc, memory, out);
}